// Round 2
// baseline (287.767 us; speedup 1.0000x reference)
//
#include <hip/hip_runtime.h>
#include <hip/hip_bf16.h>

typedef __bf16 bf16_t;
typedef __bf16 bf16x4 __attribute__((ext_vector_type(4)));
typedef __bf16 bf16x8 __attribute__((ext_vector_type(8)));
typedef float floatx16 __attribute__((ext_vector_type(16)));

#define SEQ    8192
#define DM     1024
#define NHEADS 16
#define HDIM   64

// async global->LDS, 16B per lane; LDS dest is wave-uniform base + lane*16
__device__ __forceinline__ void async_ld16(bf16_t* lds, const bf16_t* g) {
  __builtin_amdgcn_global_load_lds(
      (__attribute__((address_space(1))) void*)g,
      (__attribute__((address_space(3))) void*)lds, 16, 0, 0);
}

// one launch converts x (8192 blocks) + 4 weight matrices (1024 blocks each)
__global__ __launch_bounds__(256)
void cvt_all(const float* __restrict__ x,  const float* __restrict__ qw,
             const float* __restrict__ kw, const float* __restrict__ vw,
             const float* __restrict__ ow,
             bf16_t* __restrict__ Xb,  bf16_t* __restrict__ QWb,
             bf16_t* __restrict__ KWb, bf16_t* __restrict__ VWb,
             bf16_t* __restrict__ OWb) {
  const int b = blockIdx.x;
  const float* in; bf16_t* out; int g;
  if (b < 8192) { in = x; out = Xb; g = b; }
  else {
    const int w  = (b - 8192) >> 10;
    const int wb = (b - 8192) & 1023;
    switch (w) {
      case 0:  in = qw; out = QWb; break;
      case 1:  in = kw; out = KWb; break;
      case 2:  in = vw; out = VWb; break;
      default: in = ow; out = OWb; break;
    }
    g = wb;
  }
  const int idx = (g * 256 + threadIdx.x) * 4;
  float4 v = *(const float4*)(in + idx);
  bf16x4 o = { (bf16_t)v.x, (bf16_t)v.y, (bf16_t)v.z, (bf16_t)v.w };
  *(bf16x4*)(out + idx) = o;
}

// ---------- GEMM core: 256x256 tile, BK=32, 8 waves of 128x64 ----------
// Round-2 theory: rounds 0/1 were LDS-BW-bound (wave 64x64 reads (m+n)=4KB per
// 2KB of MFMA work -> ~36% MfmaUtil ceiling; measured 34/28%). Wave 128x64
// halves LDS-read bytes per FLOP (ceiling ~50%). Pipelining: triple-buffered
// LDS (3x32KB), depth-2 prefetch, COUNTED vmcnt(4) at tile end (never drains
// to 0 in steady state -- round-1's vmcnt(0)-per-tile was the T4 failure).
// Raw s_barrier only; the single correctness fence is vmcnt-then-barrier at
// tile end (all 8 waves' 4 loads for tile kt+1 complete; kt+2's stay in
// flight). Buffer recycle distance: issues for kt+2 target buf[(kt-1)%3],
// whose readers all passed the end-of-(kt-1) barrier. Frag/swizzle algebra
// carried from the verified round-0 kernel, re-derived for 32-elem rows:
//   A/B frag: m=lane&31, k=(lane>>5)*8+j; chunk ck = ks*2+half (4 chunks/row)
//   LDS slot(r,c) = c ^ (r&3); staging source chunk = (lane&3)^(srow&3)
//   (linear LDS dest + inverse-swizzled global source + swizzled read).
//   C/D: col=lane&31, row=(reg&3)+8*(reg>>2)+4*(lane>>5)  [m74/m101].
template <typename OutT>
__device__ __forceinline__ void gemm_core_256x256(
    const bf16_t* __restrict__ A,      // full matrix; rows blockIdx.x*256..
    const bf16_t* __restrict__ B,      // pre-offset to this block's 256-row panel
    OutT* __restrict__ C,              // pre-offset to col0; row stride DM
    float scl)
{
  constexpr int Kd = DM;               // 1024
  constexpr int NT = Kd / 32;          // 32 K-tiles
  __shared__ __attribute__((aligned(16))) bf16_t sA[3][256 * 32];  // 48 KB
  __shared__ __attribute__((aligned(16))) bf16_t sB[3][256 * 32];  // 48 KB

  const int tid  = threadIdx.x;
  const int wave = tid >> 6;           // 0..7
  const int lane = tid & 63;
  const int l31  = lane & 31;
  const int half = lane >> 5;
  const int wm   = wave >> 2;          // 0..1 -> A rows wm*128..+128
  const int wn   = wave & 3;           // 0..3 -> B rows wn*64..+64

  // staging: wave stages A rows [32w,32w+32) and B rows [32w,32w+32) per tile
  // (two 16-row 1KB loads each). 16-row load: lane -> row lane>>2, source
  // chunk (lane&3)^(row&3) so LDS slot s of row r holds global chunk s^(r&3).
  const int srow = lane >> 2;                       // 0..15 within a load
  const int gc   = (lane & 3) ^ (srow & 3);
  const bf16_t* Ag = A + ((size_t)blockIdx.x * 256 + wave * 32 + srow) * Kd + gc * 8;
  const bf16_t* Bg = B + ((size_t)wave * 32 + srow) * Kd + gc * 8;

  floatx16 acc[4][2];
  #pragma unroll
  for (int i = 0; i < 4; ++i)
    #pragma unroll
    for (int j = 0; j < 2; ++j)
      acc[i][j] = (floatx16)(0.0f);

  auto stageA = [&](int b, int kt2) {
    const size_t ko = (size_t)kt2 * 32;
    async_ld16(&sA[b][(wave * 32)      * 32], Ag + ko);
    async_ld16(&sA[b][(wave * 32 + 16) * 32], Ag + (size_t)16 * Kd + ko);
  };
  auto stageB = [&](int b, int kt2) {
    const size_t ko = (size_t)kt2 * 32;
    async_ld16(&sB[b][(wave * 32)      * 32], Bg + ko);
    async_ld16(&sB[b][(wave * 32 + 16) * 32], Bg + (size_t)16 * Kd + ko);
  };

  auto phase = [&](int cur, int ks) {
    const int slot = ((ks * 2 + half) ^ (l31 & 3)) * 8;
    bf16x8 af[4], bfr[2];
    #pragma unroll
    for (int mb = 0; mb < 4; ++mb)
      af[mb] = *(const bf16x8*)&sA[cur][(wm * 128 + mb * 32 + l31) * 32 + slot];
    #pragma unroll
    for (int nb = 0; nb < 2; ++nb)
      bfr[nb] = *(const bf16x8*)&sB[cur][(wn * 64 + nb * 32 + l31) * 32 + slot];
    __builtin_amdgcn_s_barrier();      // phase alignment only (no data dep)
    __builtin_amdgcn_s_setprio(1);
    #pragma unroll
    for (int mb = 0; mb < 4; ++mb)
      #pragma unroll
      for (int nb = 0; nb < 2; ++nb)
        acc[mb][nb] = __builtin_amdgcn_mfma_f32_32x32x16_bf16(af[mb], bfr[nb], acc[mb][nb], 0, 0, 0);
    __builtin_amdgcn_s_setprio(0);
  };

  // prologue: stage tiles 0 and 1 (8 loads/wave); wait for tile 0 (4 remain)
  stageA(0, 0); stageB(0, 0);
  stageA(1, 1); stageB(1, 1);
  asm volatile("s_waitcnt vmcnt(4)" ::: "memory");
  __builtin_amdgcn_s_barrier();

  int cur = 0;
  for (int kt = 0; kt < NT; ++kt) {
    const int  nb2 = (cur >= 1) ? cur - 1 : 2;   // (cur+2)%3
    const bool pre = (kt + 2 < NT);

    if (pre) stageA(nb2, kt + 2);
    phase(cur, 0);
    if (pre) stageB(nb2, kt + 2);
    phase(cur, 1);

    if (kt < NT - 1) {
      // counted wait: steady state leaves tile kt+2's 4 loads in flight
      if (kt < NT - 2) asm volatile("s_waitcnt vmcnt(4)" ::: "memory");
      else             asm volatile("s_waitcnt vmcnt(0)" ::: "memory");
      __builtin_amdgcn_s_barrier();
    }
    cur = (cur == 2) ? 0 : cur + 1;
  }

  // C/D: col = lane&31, row = (reg&3) + 8*(reg>>2) + 4*(lane>>5)
  const int crow0 = (int)blockIdx.x * 256 + wm * 128 + 4 * half;
  const int ccol0 = wn * 64 + l31;
  #pragma unroll
  for (int mb = 0; mb < 4; ++mb)
    #pragma unroll
    for (int nb = 0; nb < 2; ++nb)
      #pragma unroll
      for (int r = 0; r < 16; ++r) {
        const int row = crow0 + mb * 32 + (r & 3) + 8 * (r >> 2);
        C[(size_t)row * DM + ccol0 + nb * 32] = (OutT)(acc[mb][nb][r] * scl);
      }
}

// QKV fused: W = QWb (3072x1024, Q/K/V weight rows contiguous in workspace);
// C = Qb (Q/K/V output buffers contiguous). blockIdx.y in 0..11.
__global__ __launch_bounds__(512, 2)
void gemm_qkv(const bf16_t* __restrict__ A, const bf16_t* __restrict__ W,
              bf16_t* __restrict__ Cq)
{
  const int y   = blockIdx.y;
  const int mat = y >> 2;                              // 0=Q 1=K 2=V
  const bf16_t* B = W + (size_t)y * 256 * DM;
  bf16_t*       C = Cq + (size_t)mat * SEQ * DM + (y & 3) * 256;
  const float scl = (mat == 0) ? 0.125f : 1.0f;        // fold 1/sqrt(64) into Q
  gemm_core_256x256<bf16_t>(A, B, C, scl);
}

__global__ __launch_bounds__(512, 2)
void gemm_out(const bf16_t* __restrict__ A, const bf16_t* __restrict__ B,
              float* __restrict__ C)
{
  const bf16_t* Bp = B + (size_t)blockIdx.y * 256 * DM;
  float*        Cp = C + blockIdx.y * 256;
  gemm_core_256x256<float>(A, Bp, Cp, 1.0f);
}

// ---------- Attention: SPLIT-WAVE (unchanged this round) ----------
// 2 waves per query: wave sub handles positions t = sub, sub+2, ...; partial
// (m, l, acc[16]) states merge through LDS with one exp-rescale.
// Lane L owns dims [16L,16L+16) (head = L>>2); Q arrives pre-scaled.
__global__ __launch_bounds__(256)
void dilated_attn(const bf16_t* __restrict__ Q, const bf16_t* __restrict__ K,
                  const bf16_t* __restrict__ V, bf16_t* O)
{
  __shared__ float sM[2][64];
  __shared__ float sL[2][64];
  __shared__ float sAcc[2][64][17];   // stride 17: gcd(17,32)=1 -> conflict-free

  const int lane = threadIdx.x & 63;
  const int wv   = threadIdx.x >> 6;   // 0..3
  const int ql   = wv >> 1;            // query within block (0,1)
  const int sub  = wv & 1;             // position-parity subset
  const int qb   = (blockIdx.x & 7) * 512 + (blockIdx.x >> 3);  // XCD-affinity swizzle
  const int i    = qb * 2 + ql;
  const size_t base = (size_t)i * DM + lane * 16;

  bf16x8 q0 = *(const bf16x8*)(Q + base);
  bf16x8 q1 = *(const bf16x8*)(Q + base + 8);
  float qf[16];
  #pragma unroll
  for (int j = 0; j < 8; ++j) { qf[j] = (float)q0[j]; qf[j + 8] = (float)q1[j]; }

  // npos = 1 (i==0) else floor(log2 i) + 2   (wave-uniform)
  const int npos = (i == 0) ? 1 : (33 - __builtin_clz((unsigned)i));
  auto pos_addr = [&](int t) -> size_t {
    const int off = (t == 0) ? 0 : (1 << (t - 1));
    return (size_t)(i - off) * DM + lane * 16;
  };

  float m = -INFINITY, l = 0.0f;
  float acc[16];
  #pragma unroll
  for (int j = 0; j < 16; ++j) acc[j] = 0.0f;

  int t = sub;
  if (t < npos) {
    size_t a = pos_addr(t);
    bf16x8 k0 = *(const bf16x8*)(K + a), k1 = *(const bf16x8*)(K + a + 8);
    bf16x8 v0 = *(const bf16x8*)(V + a), v1 = *(const bf16x8*)(V + a + 8);
    while (true) {
      const int tn = t + 2;
      const bool more = (tn < npos);       // wave-uniform
      bf16x8 nk0, nk1, nv0, nv1;
      if (more) {                          // prefetch next position in subset
        const size_t na = pos_addr(tn);
        nk0 = *(const bf16x8*)(K + na); nk1 = *(const bf16x8*)(K + na + 8);
        nv0 = *(const bf16x8*)(V + na); nv1 = *(const bf16x8*)(V + na + 8);
      }

      float sc = 0.0f;
      #pragma unroll
      for (int j = 0; j < 8; ++j) sc += qf[j] * (float)k0[j] + qf[j + 8] * (float)k1[j];
      sc += __shfl_xor(sc, 1, 64);         // sum across the 4 lanes of this head
      sc += __shfl_xor(sc, 2, 64);

      float mn = fmaxf(m, sc);
      float co = __expf(m - mn);
      float w  = __expf(sc - mn);
      l = l * co + w;
      m = mn;
      #pragma unroll
      for (int j = 0; j < 8; ++j) {
        acc[j]     = acc[j]     * co + w * (float)v0[j];
        acc[j + 8] = acc[j + 8] * co + w * (float)v1[j];
      }

      if (!more) break;
      k0 = nk0; k1 = nk1; v0 = nv0; v1 = nv1;
      t = tn;
    }
  }

  // merge the two partial states per query
  if (sub == 1) {
    sM[ql][lane] = m;
    sL[ql][lane] = l;
    #pragma unroll
    for (int j = 0; j < 16; ++j) sAcc[ql][lane][j] = acc[j];
  }
  __syncthreads();
  if (sub == 0) {
    const float mb = sM[ql][lane], lb = sL[ql][lane];
    const float mt = fmaxf(m, mb);           // m finite (t=0 always valid for sub=0)
    const float ca = __expf(m - mt);
    const float cb = __expf(mb - mt);        // mb=-inf (i==0 case) -> cb=0, exact no-op
    const float inv = 1.0f / (l * ca + lb * cb);
    bf16x8 o0, o1;
    #pragma unroll
    for (int j = 0; j < 8; ++j) {
      o0[j] = (bf16_t)((acc[j]     * ca + sAcc[ql][lane][j]     * cb) * inv);
      o1[j] = (bf16_t)((acc[j + 8] * ca + sAcc[ql][lane][j + 8] * cb) * inv);
    }
    *(bf16x8*)(O + base)     = o0;
    *(bf16x8*)(O + base + 8) = o1;
  }
}

extern "C" void kernel_launch(void* const* d_in, const int* in_sizes, int n_in,
                              void* d_out, int out_size, void* d_ws, size_t ws_size,
                              hipStream_t stream) {
  (void)in_sizes; (void)n_in; (void)out_size; (void)ws_size;
  const float* x  = (const float*)d_in[0];
  const float* qw = (const float*)d_in[1];
  const float* kw = (const float*)d_in[2];
  const float* vw = (const float*)d_in[3];
  const float* ow = (const float*)d_in[4];
  // d_in[5] (positions) and d_in[6] (attend_mask) recomputed analytically in-kernel
  float* out = (float*)d_out;

  bf16_t* Xb  = (bf16_t*)d_ws;                       // 8192x1024
  bf16_t* Qb  = Xb  + (size_t)SEQ * DM;
  bf16_t* Kb  = Qb  + (size_t)SEQ * DM;
  bf16_t* Vb  = Kb  + (size_t)SEQ * DM;
  bf16_t* QWb = Vb  + (size_t)SEQ * DM;              // 1024x1024 x4, contiguous
  bf16_t* KWb = QWb + (size_t)DM * DM;
  bf16_t* VWb = KWb + (size_t)DM * DM;
  bf16_t* OWb = VWb + (size_t)DM * DM;
  bf16_t* AO  = Qb;  // alias Q: each attn block reads its own q rows before writing them

  cvt_all<<<dim3(8192 + 4096), dim3(256), 0, stream>>>(x, qw, kw, vw, ow,
                                                       Xb, QWb, KWb, VWb, OWb);

  // QKV fused over N=3072 (QWb/KWb/VWb contiguous; Qb/Kb/Vb contiguous)
  gemm_qkv<<<dim3(SEQ / 256, 12), dim3(512), 0, stream>>>(Xb, QWb, Qb);
  dilated_attn<<<dim3(SEQ / 2), dim3(256), 0, stream>>>(Qb, Kb, Vb, AO);
  gemm_out<<<dim3(SEQ / 256, DM / 256), dim3(512), 0, stream>>>(AO, OWb, out);
}

// Round 3
// 270.061 us; speedup vs baseline: 1.0656x; 1.0656x over previous
//
#include <hip/hip_runtime.h>
#include <hip/hip_bf16.h>

typedef __bf16 bf16_t;
typedef __bf16 bf16x4 __attribute__((ext_vector_type(4)));
typedef __bf16 bf16x8 __attribute__((ext_vector_type(8)));
typedef float floatx16 __attribute__((ext_vector_type(16)));

#define SEQ    8192
#define DM     1024
#define NHEADS 16
#define HDIM   64

// async global->LDS, 16B per lane; LDS dest is wave-uniform base + lane*16
__device__ __forceinline__ void async_ld16(bf16_t* lds, const bf16_t* g) {
  __builtin_amdgcn_global_load_lds(
      (__attribute__((address_space(1))) void*)g,
      (__attribute__((address_space(3))) void*)lds, 16, 0, 0);
}

// one launch converts x (8192 blocks) + 4 weight matrices (1024 blocks each)
__global__ __launch_bounds__(256)
void cvt_all(const float* __restrict__ x,  const float* __restrict__ qw,
             const float* __restrict__ kw, const float* __restrict__ vw,
             const float* __restrict__ ow,
             bf16_t* __restrict__ Xb,  bf16_t* __restrict__ QWb,
             bf16_t* __restrict__ KWb, bf16_t* __restrict__ VWb,
             bf16_t* __restrict__ OWb) {
  const int b = blockIdx.x;
  const float* in; bf16_t* out; int g;
  if (b < 8192) { in = x; out = Xb; g = b; }
  else {
    const int w  = (b - 8192) >> 10;
    const int wb = (b - 8192) & 1023;
    switch (w) {
      case 0:  in = qw; out = QWb; break;
      case 1:  in = kw; out = KWb; break;
      case 2:  in = vw; out = VWb; break;
      default: in = ow; out = OWb; break;
    }
    g = wb;
  }
  const int idx = (g * 256 + threadIdx.x) * 4;
  float4 v = *(const float4*)(in + idx);
  bf16x4 o = { (bf16_t)v.x, (bf16_t)v.y, (bf16_t)v.z, (bf16_t)v.w };
  *(bf16x4*)(out + idx) = o;
}

// ---------- GEMM core: 256x256 tile, BK=32, 8 waves of 128x64 ----------
// Round-3 fix: round-2's swizzle key (r&3) was WRONG for 64B rows. Granule
// position in the 128B bank period is g=(4*row+slot)%8; key (r&3) collapsed
// 16 lanes onto 2 granules -> 8-way conflict (SQ_LDS_BANK_CONFLICT 14.16M,
// MfmaUtil 18%). Correct key (round-0 gemm_out, verified): key(r)=(r>>1)&3.
// Then g(l) = (4l + c^((l>>1)&3))%8 is a permutation over each 8-lane group
// -> 4 lanes/granule per 32-lane half = 4-cycle minimum, conflict-free.
// Structure (kept from round 2): triple-buffered LDS (3x32KB A + 3x32KB B),
// depth-2 prefetch, COUNTED vmcnt(4) at tile end (tile kt+1 complete, kt+2's
// 4 loads stay in flight -- T4). Per-phase raw s_barrier + setprio around the
// MFMA cluster (T3/T5). Wave tile 128x64: LDS ceiling ~67% MfmaUtil
// (256 matrix-cy/SIMD vs 384 LDS-read-cy/CU per K-tile).
// Frag algebra (verified m74/m101): A/B frag m=lane&31, k=(lane>>5)*8+j;
// C/D col=lane&31, row=(reg&3)+8*(reg>>2)+4*(lane>>5).
template <typename OutT>
__device__ __forceinline__ void gemm_core_256x256(
    const bf16_t* __restrict__ A,      // full matrix; rows blockIdx.x*256..
    const bf16_t* __restrict__ B,      // pre-offset to this block's 256-row panel
    OutT* __restrict__ C,              // pre-offset to col0; row stride DM
    float scl)
{
  constexpr int Kd = DM;               // 1024
  constexpr int NT = Kd / 32;          // 32 K-tiles
  __shared__ __attribute__((aligned(16))) bf16_t sA[3][256 * 32];  // 48 KB
  __shared__ __attribute__((aligned(16))) bf16_t sB[3][256 * 32];  // 48 KB

  const int tid  = threadIdx.x;
  const int wave = tid >> 6;           // 0..7
  const int lane = tid & 63;
  const int l31  = lane & 31;
  const int half = lane >> 5;
  const int wm   = wave >> 2;          // 0..1 -> A rows wm*128..+128
  const int wn   = wave & 3;           // 0..3 -> B rows wn*64..+64

  // staging: wave stages A rows [32w,32w+32) and B rows [32w,32w+32) per tile
  // (two 16-row 1KB loads each). 16-row load: lane -> row lane>>2, slot lane&3;
  // source chunk (lane&3)^((row>>1)&3) so LDS slot s of row r holds global
  // chunk s^((r>>1)&3)  (linear LDS dest + inverse-swizzled source).
  const int srow = lane >> 2;                       // 0..15 within a load
  const int gc   = (lane & 3) ^ ((srow >> 1) & 3);
  const bf16_t* Ag = A + ((size_t)blockIdx.x * 256 + wave * 32 + srow) * Kd + gc * 8;
  const bf16_t* Bg = B + ((size_t)wave * 32 + srow) * Kd + gc * 8;

  floatx16 acc[4][2];
  #pragma unroll
  for (int i = 0; i < 4; ++i)
    #pragma unroll
    for (int j = 0; j < 2; ++j)
      acc[i][j] = (floatx16)(0.0f);

  auto stageA = [&](int b, int kt2) {
    const size_t ko = (size_t)kt2 * 32;
    async_ld16(&sA[b][(wave * 32)      * 32], Ag + ko);
    async_ld16(&sA[b][(wave * 32 + 16) * 32], Ag + (size_t)16 * Kd + ko);
  };
  auto stageB = [&](int b, int kt2) {
    const size_t ko = (size_t)kt2 * 32;
    async_ld16(&sB[b][(wave * 32)      * 32], Bg + ko);
    async_ld16(&sB[b][(wave * 32 + 16) * 32], Bg + (size_t)16 * Kd + ko);
  };

  auto phase = [&](int cur, int ks) {
    // read slot = ck ^ ((row>>1)&3); reader rows = base + l31 with base%4==0
    const int slot = ((ks * 2 + half) ^ ((l31 >> 1) & 3)) * 8;
    bf16x8 af[4], bfr[2];
    #pragma unroll
    for (int mb = 0; mb < 4; ++mb)
      af[mb] = *(const bf16x8*)&sA[cur][(wm * 128 + mb * 32 + l31) * 32 + slot];
    #pragma unroll
    for (int nb = 0; nb < 2; ++nb)
      bfr[nb] = *(const bf16x8*)&sB[cur][(wn * 64 + nb * 32 + l31) * 32 + slot];
    __builtin_amdgcn_s_barrier();      // phase alignment only (no data dep)
    __builtin_amdgcn_s_setprio(1);
    #pragma unroll
    for (int mb = 0; mb < 4; ++mb)
      #pragma unroll
      for (int nb = 0; nb < 2; ++nb)
        acc[mb][nb] = __builtin_amdgcn_mfma_f32_32x32x16_bf16(af[mb], bfr[nb], acc[mb][nb], 0, 0, 0);
    __builtin_amdgcn_s_setprio(0);
  };

  // prologue: stage tiles 0 and 1 (8 loads/wave); wait for tile 0 (4 remain)
  stageA(0, 0); stageB(0, 0);
  stageA(1, 1); stageB(1, 1);
  asm volatile("s_waitcnt vmcnt(4)" ::: "memory");
  __builtin_amdgcn_s_barrier();

  int cur = 0;
  for (int kt = 0; kt < NT; ++kt) {
    const int  nb2 = (cur >= 1) ? cur - 1 : 2;   // (cur+2)%3
    const bool pre = (kt + 2 < NT);

    if (pre) stageA(nb2, kt + 2);
    phase(cur, 0);
    if (pre) stageB(nb2, kt + 2);
    phase(cur, 1);

    if (kt < NT - 1) {
      // counted wait: steady state leaves tile kt+2's 4 loads in flight
      if (kt < NT - 2) asm volatile("s_waitcnt vmcnt(4)" ::: "memory");
      else             asm volatile("s_waitcnt vmcnt(0)" ::: "memory");
      __builtin_amdgcn_s_barrier();
    }
    cur = (cur == 2) ? 0 : cur + 1;
  }

  // C/D: col = lane&31, row = (reg&3) + 8*(reg>>2) + 4*(lane>>5)
  const int crow0 = (int)blockIdx.x * 256 + wm * 128 + 4 * half;
  const int ccol0 = wn * 64 + l31;
  #pragma unroll
  for (int mb = 0; mb < 4; ++mb)
    #pragma unroll
    for (int nb = 0; nb < 2; ++nb)
      #pragma unroll
      for (int r = 0; r < 16; ++r) {
        const int row = crow0 + mb * 32 + (r & 3) + 8 * (r >> 2);
        C[(size_t)row * DM + ccol0 + nb * 32] = (OutT)(acc[mb][nb][r] * scl);
      }
}

// QKV fused: W = QWb (3072x1024, Q/K/V weight rows contiguous in workspace);
// C = Qb (Q/K/V output buffers contiguous). blockIdx.y in 0..11.
__global__ __launch_bounds__(512, 2)
void gemm_qkv(const bf16_t* __restrict__ A, const bf16_t* __restrict__ W,
              bf16_t* __restrict__ Cq)
{
  const int y   = blockIdx.y;
  const int mat = y >> 2;                              // 0=Q 1=K 2=V
  const bf16_t* B = W + (size_t)y * 256 * DM;
  bf16_t*       C = Cq + (size_t)mat * SEQ * DM + (y & 3) * 256;
  const float scl = (mat == 0) ? 0.125f : 1.0f;        // fold 1/sqrt(64) into Q
  gemm_core_256x256<bf16_t>(A, B, C, scl);
}

__global__ __launch_bounds__(512, 2)
void gemm_out(const bf16_t* __restrict__ A, const bf16_t* __restrict__ B,
              float* __restrict__ C)
{
  const bf16_t* Bp = B + (size_t)blockIdx.y * 256 * DM;
  float*        Cp = C + blockIdx.y * 256;
  gemm_core_256x256<float>(A, Bp, Cp, 1.0f);
}

// ---------- Attention: SPLIT-WAVE (unchanged this round) ----------
// 2 waves per query: wave sub handles positions t = sub, sub+2, ...; partial
// (m, l, acc[16]) states merge through LDS with one exp-rescale.
// Lane L owns dims [16L,16L+16) (head = L>>2); Q arrives pre-scaled.
__global__ __launch_bounds__(256)
void dilated_attn(const bf16_t* __restrict__ Q, const bf16_t* __restrict__ K,
                  const bf16_t* __restrict__ V, bf16_t* O)
{
  __shared__ float sM[2][64];
  __shared__ float sL[2][64];
  __shared__ float sAcc[2][64][17];   // stride 17: gcd(17,32)=1 -> conflict-free

  const int lane = threadIdx.x & 63;
  const int wv   = threadIdx.x >> 6;   // 0..3
  const int ql   = wv >> 1;            // query within block (0,1)
  const int sub  = wv & 1;             // position-parity subset
  const int qb   = (blockIdx.x & 7) * 512 + (blockIdx.x >> 3);  // XCD-affinity swizzle
  const int i    = qb * 2 + ql;
  const size_t base = (size_t)i * DM + lane * 16;

  bf16x8 q0 = *(const bf16x8*)(Q + base);
  bf16x8 q1 = *(const bf16x8*)(Q + base + 8);
  float qf[16];
  #pragma unroll
  for (int j = 0; j < 8; ++j) { qf[j] = (float)q0[j]; qf[j + 8] = (float)q1[j]; }

  // npos = 1 (i==0) else floor(log2 i) + 2   (wave-uniform)
  const int npos = (i == 0) ? 1 : (33 - __builtin_clz((unsigned)i));
  auto pos_addr = [&](int t) -> size_t {
    const int off = (t == 0) ? 0 : (1 << (t - 1));
    return (size_t)(i - off) * DM + lane * 16;
  };

  float m = -INFINITY, l = 0.0f;
  float acc[16];
  #pragma unroll
  for (int j = 0; j < 16; ++j) acc[j] = 0.0f;

  int t = sub;
  if (t < npos) {
    size_t a = pos_addr(t);
    bf16x8 k0 = *(const bf16x8*)(K + a), k1 = *(const bf16x8*)(K + a + 8);
    bf16x8 v0 = *(const bf16x8*)(V + a), v1 = *(const bf16x8*)(V + a + 8);
    while (true) {
      const int tn = t + 2;
      const bool more = (tn < npos);       // wave-uniform
      bf16x8 nk0, nk1, nv0, nv1;
      if (more) {                          // prefetch next position in subset
        const size_t na = pos_addr(tn);
        nk0 = *(const bf16x8*)(K + na); nk1 = *(const bf16x8*)(K + na + 8);
        nv0 = *(const bf16x8*)(V + na); nv1 = *(const bf16x8*)(V + na + 8);
      }

      float sc = 0.0f;
      #pragma unroll
      for (int j = 0; j < 8; ++j) sc += qf[j] * (float)k0[j] + qf[j + 8] * (float)k1[j];
      sc += __shfl_xor(sc, 1, 64);         // sum across the 4 lanes of this head
      sc += __shfl_xor(sc, 2, 64);

      float mn = fmaxf(m, sc);
      float co = __expf(m - mn);
      float w  = __expf(sc - mn);
      l = l * co + w;
      m = mn;
      #pragma unroll
      for (int j = 0; j < 8; ++j) {
        acc[j]     = acc[j]     * co + w * (float)v0[j];
        acc[j + 8] = acc[j + 8] * co + w * (float)v1[j];
      }

      if (!more) break;
      k0 = nk0; k1 = nk1; v0 = nv0; v1 = nv1;
      t = tn;
    }
  }

  // merge the two partial states per query
  if (sub == 1) {
    sM[ql][lane] = m;
    sL[ql][lane] = l;
    #pragma unroll
    for (int j = 0; j < 16; ++j) sAcc[ql][lane][j] = acc[j];
  }
  __syncthreads();
  if (sub == 0) {
    const float mb = sM[ql][lane], lb = sL[ql][lane];
    const float mt = fmaxf(m, mb);           // m finite (t=0 always valid for sub=0)
    const float ca = __expf(m - mt);
    const float cb = __expf(mb - mt);        // mb=-inf (i==0 case) -> cb=0, exact no-op
    const float inv = 1.0f / (l * ca + lb * cb);
    bf16x8 o0, o1;
    #pragma unroll
    for (int j = 0; j < 8; ++j) {
      o0[j] = (bf16_t)((acc[j]     * ca + sAcc[ql][lane][j]     * cb) * inv);
      o1[j] = (bf16_t)((acc[j + 8] * ca + sAcc[ql][lane][j + 8] * cb) * inv);
    }
    *(bf16x8*)(O + base)     = o0;
    *(bf16x8*)(O + base + 8) = o1;
  }
}

extern "C" void kernel_launch(void* const* d_in, const int* in_sizes, int n_in,
                              void* d_out, int out_size, void* d_ws, size_t ws_size,
                              hipStream_t stream) {
  (void)in_sizes; (void)n_in; (void)out_size; (void)ws_size;
  const float* x  = (const float*)d_in[0];
  const float* qw = (const float*)d_in[1];
  const float* kw = (const float*)d_in[2];
  const float* vw = (const float*)d_in[3];
  const float* ow = (const float*)d_in[4];
  // d_in[5] (positions) and d_in[6] (attend_mask) recomputed analytically in-kernel
  float* out = (float*)d_out;

  bf16_t* Xb  = (bf16_t*)d_ws;                       // 8192x1024
  bf16_t* Qb  = Xb  + (size_t)SEQ * DM;
  bf16_t* Kb  = Qb  + (size_t)SEQ * DM;
  bf16_t* Vb  = Kb  + (size_t)SEQ * DM;
  bf16_t* QWb = Vb  + (size_t)SEQ * DM;              // 1024x1024 x4, contiguous
  bf16_t* KWb = QWb + (size_t)DM * DM;
  bf16_t* VWb = KWb + (size_t)DM * DM;
  bf16_t* OWb = VWb + (size_t)DM * DM;
  bf16_t* AO  = Qb;  // alias Q: each attn block reads its own q rows before writing them

  cvt_all<<<dim3(8192 + 4096), dim3(256), 0, stream>>>(x, qw, kw, vw, ow,
                                                       Xb, QWb, KWb, VWb, OWb);

  // QKV fused over N=3072 (QWb/KWb/VWb contiguous; Qb/Kb/Vb contiguous)
  gemm_qkv<<<dim3(SEQ / 256, 12), dim3(512), 0, stream>>>(Xb, QWb, Qb);
  dilated_attn<<<dim3(SEQ / 2), dim3(256), 0, stream>>>(Qb, Kb, Vb, AO);
  gemm_out<<<dim3(SEQ / 256, DM / 256), dim3(512), 0, stream>>>(AO, OWb, out);
}

// Round 4
// 237.182 us; speedup vs baseline: 1.2133x; 1.1386x over previous
//
#include <hip/hip_runtime.h>
#include <hip/hip_bf16.h>

typedef __bf16 bf16_t;
typedef __bf16 bf16x4 __attribute__((ext_vector_type(4)));
typedef __bf16 bf16x8 __attribute__((ext_vector_type(8)));
typedef float floatx16 __attribute__((ext_vector_type(16)));

#define SEQ    8192
#define DM     1024
#define NHEADS 16
#define HDIM   64

// async global->LDS, 16B per lane; LDS dest is wave-uniform base + lane*16
__device__ __forceinline__ void async_ld16(bf16_t* lds, const bf16_t* g) {
  __builtin_amdgcn_global_load_lds(
      (__attribute__((address_space(1))) void*)g,
      (__attribute__((address_space(3))) void*)lds, 16, 0, 0);
}

// one launch converts x (8192 blocks) + 4 weight matrices (1024 blocks each)
__global__ __launch_bounds__(256)
void cvt_all(const float* __restrict__ x,  const float* __restrict__ qw,
             const float* __restrict__ kw, const float* __restrict__ vw,
             const float* __restrict__ ow,
             bf16_t* __restrict__ Xb,  bf16_t* __restrict__ QWb,
             bf16_t* __restrict__ KWb, bf16_t* __restrict__ VWb,
             bf16_t* __restrict__ OWb) {
  const int b = blockIdx.x;
  const float* in; bf16_t* out; int g;
  if (b < 8192) { in = x; out = Xb; g = b; }
  else {
    const int w  = (b - 8192) >> 10;
    const int wb = (b - 8192) & 1023;
    switch (w) {
      case 0:  in = qw; out = QWb; break;
      case 1:  in = kw; out = KWb; break;
      case 2:  in = vw; out = VWb; break;
      default: in = ow; out = OWb; break;
    }
    g = wb;
  }
  const int idx = (g * 256 + threadIdx.x) * 4;
  float4 v = *(const float4*)(in + idx);
  bf16x4 o = { (bf16_t)v.x, (bf16_t)v.y, (bf16_t)v.z, (bf16_t)v.w };
  *(bf16x4*)(out + idx) = o;
}

// ---------- GEMM core: round-0 PROVEN structure, scaled wave tile ----------
// Round-4 theory: rounds 1-3's in-flight-prefetch schedules are defeated by
// compiler-inserted s_waitcnt vmcnt(0) before ds_reads (global_load_lds writes
// into the SAME __shared__ array with runtime buffer index -> conservative
// alias ordering) -> ~5000 cy/K-tile pure stall. Revert to the verified
// round-0 sync pattern (stage -> __syncthreads -> 4 sub-steps -> __syncthreads;
// NO outstanding loads during reads; 3 co-resident blocks/CU provide the
// inter-block latency overlap, m114). Improvement kept: wave tile 128x64
// (BM=256) reads 6KB LDS per 8 MFMA vs 64x64's 4KB per 4 -> 1.5x better
// compute-per-LDS-byte; ceiling ~50-67% MfmaUtil vs round-0's ~36%.
// All index/swizzle algebra VERBATIM from the verified round-0 kernel
// (128B rows, XOR-8): staging source chunk (lane&7)^((lane>>3)&7) with linear
// LDS dest -> slot s of row r holds chunk s^(r&7); read slot = (ck^(l31&7))*8.
// A/B frag: m=lane&31, k=(lane>>5)*8+j. C/D: col=lane&31,
// row=(reg&3)+8*(reg>>2)+4*(lane>>5)  [m74/m101].
// BM=256: 4 waves as 2x2, wave tile 128x64 (mb 0..3). BM=128: wave 64x64
// (mb 0..1) == round-0 geometry exactly.
template <int BM, typename OutT>
__device__ __forceinline__ void gemm_core(
    const bf16_t* __restrict__ A, const bf16_t* __restrict__ B,
    OutT* __restrict__ C, float scl)
{
  constexpr int Kd  = DM;
  constexpr int MBF = BM / 64;        // m-fragments per wave (4 or 2)
  __shared__ __attribute__((aligned(16))) bf16_t sA[BM * 64];    // 32/16 KB
  __shared__ __attribute__((aligned(16))) bf16_t sB[128 * 64];   // 16 KB

  const int tid  = threadIdx.x;
  const int wave = tid >> 6;          // 0..3
  const int lane = tid & 63;
  const int l31  = lane & 31;
  const int half = lane >> 5;
  const int wm   = wave >> 1;         // 0..1 -> A rows wm*(BM/2)
  const int wn   = wave & 1;          // 0..1 -> B rows wn*64

  // staging (round-0 verbatim): wave stages 32-row chunks; one async op covers
  // 8 rows x 128B. Source chunk gc = slot ^ (row&7) (inverse swizzle).
  const int gc = (lane & 7) ^ ((lane >> 3) & 7);
  const bf16_t* Ag = A + ((size_t)blockIdx.x * BM + wave * 32 + (lane >> 3)) * Kd + gc * 8;
  const bf16_t* Bg = B + ((size_t)blockIdx.y * 128 + wave * 32 + (lane >> 3)) * Kd + gc * 8;

  floatx16 acc[MBF][2];
  #pragma unroll
  for (int i = 0; i < MBF; ++i)
    #pragma unroll
    for (int j = 0; j < 2; ++j)
      acc[i][j] = (floatx16)(0.0f);

  const int sw = l31 & 7;             // read-side swizzle key (row&7)

  for (int ko = 0; ko < Kd; ko += 64) {
    #pragma unroll
    for (int h = 0; h < BM / 128; ++h)
      #pragma unroll
      for (int n = 0; n < 4; ++n)
        async_ld16(&sA[(h * 128 + wave * 32 + n * 8) * 64],
                   Ag + ((size_t)(h * 128 + n * 8)) * Kd + ko);
    #pragma unroll
    for (int n = 0; n < 4; ++n)
      async_ld16(&sB[(wave * 32 + n * 8) * 64], Bg + (size_t)(n * 8) * Kd + ko);
    __syncthreads();   // drains vmcnt, then barrier (round-0 semantics)

    #pragma unroll
    for (int s = 0; s < 4; ++s) {       // four K=16 sub-steps
      const int slot = ((s * 2 + half) ^ sw) * 8;
      bf16x8 af[MBF], bfr[2];
      #pragma unroll
      for (int mb = 0; mb < MBF; ++mb)
        af[mb] = *(const bf16x8*)&sA[(wm * (BM / 2) + mb * 32 + l31) * 64 + slot];
      #pragma unroll
      for (int nb = 0; nb < 2; ++nb)
        bfr[nb] = *(const bf16x8*)&sB[(wn * 64 + nb * 32 + l31) * 64 + slot];

      #pragma unroll
      for (int mb = 0; mb < MBF; ++mb)
        #pragma unroll
        for (int nb = 0; nb < 2; ++nb)
          acc[mb][nb] = __builtin_amdgcn_mfma_f32_32x32x16_bf16(af[mb], bfr[nb], acc[mb][nb], 0, 0, 0);
    }

    __syncthreads();   // protect LDS before next stage overwrites
  }

  // C/D: col = lane&31, row = (reg&3) + 8*(reg>>2) + 4*(lane>>5)
  const int crow0 = (int)blockIdx.x * BM + wm * (BM / 2) + 4 * half;
  const int ccol0 = (int)blockIdx.y * 128 + wn * 64 + l31;
  #pragma unroll
  for (int mb = 0; mb < MBF; ++mb)
    #pragma unroll
    for (int nb = 0; nb < 2; ++nb)
      #pragma unroll
      for (int r = 0; r < 16; ++r) {
        const int row = crow0 + mb * 32 + (r & 3) + 8 * (r >> 2);
        C[(size_t)row * DM + ccol0 + nb * 32] = (OutT)(acc[mb][nb][r] * scl);
      }
}

// QKV: grid (32, 8, 3) = 768 blocks = exactly 3 blocks/CU x 256 CU (48KB LDS
// -> 3 co-resident), zero tail. z selects matrix.
__global__ __launch_bounds__(256)
void gemm_qkv(const bf16_t* __restrict__ A,
              const bf16_t* __restrict__ Bq, const bf16_t* __restrict__ Bk,
              const bf16_t* __restrict__ Bv,
              bf16_t* __restrict__ Cq, bf16_t* __restrict__ Ck, bf16_t* __restrict__ Cv)
{
  const bf16_t* B = (blockIdx.z == 0) ? Bq : (blockIdx.z == 1) ? Bk : Bv;
  bf16_t*       C = (blockIdx.z == 0) ? Cq : (blockIdx.z == 1) ? Ck : Cv;
  const float scl = (blockIdx.z == 0) ? 0.125f : 1.0f;   // fold 1/sqrt(64) into Q
  gemm_core<256, bf16_t>(A, B, C, scl);
}

// OUT: BM=128 (== round-0 geometry), grid (64, 8) = 512 blocks @ 2+/CU.
__global__ __launch_bounds__(256)
void gemm_out(const bf16_t* __restrict__ A, const bf16_t* __restrict__ B,
              float* __restrict__ C)
{
  gemm_core<128, float>(A, B, C, 1.0f);
}

// ---------- Attention: SPLIT-WAVE (unchanged this round) ----------
// 2 waves per query: wave sub handles positions t = sub, sub+2, ...; partial
// (m, l, acc[16]) states merge through LDS with one exp-rescale.
// Lane L owns dims [16L,16L+16) (head = L>>2); Q arrives pre-scaled.
__global__ __launch_bounds__(256)
void dilated_attn(const bf16_t* __restrict__ Q, const bf16_t* __restrict__ K,
                  const bf16_t* __restrict__ V, bf16_t* O)
{
  __shared__ float sM[2][64];
  __shared__ float sL[2][64];
  __shared__ float sAcc[2][64][17];   // stride 17: gcd(17,32)=1 -> conflict-free

  const int lane = threadIdx.x & 63;
  const int wv   = threadIdx.x >> 6;   // 0..3
  const int ql   = wv >> 1;            // query within block (0,1)
  const int sub  = wv & 1;             // position-parity subset
  const int qb   = (blockIdx.x & 7) * 512 + (blockIdx.x >> 3);  // XCD-affinity swizzle
  const int i    = qb * 2 + ql;
  const size_t base = (size_t)i * DM + lane * 16;

  bf16x8 q0 = *(const bf16x8*)(Q + base);
  bf16x8 q1 = *(const bf16x8*)(Q + base + 8);
  float qf[16];
  #pragma unroll
  for (int j = 0; j < 8; ++j) { qf[j] = (float)q0[j]; qf[j + 8] = (float)q1[j]; }

  // npos = 1 (i==0) else floor(log2 i) + 2   (wave-uniform)
  const int npos = (i == 0) ? 1 : (33 - __builtin_clz((unsigned)i));
  auto pos_addr = [&](int t) -> size_t {
    const int off = (t == 0) ? 0 : (1 << (t - 1));
    return (size_t)(i - off) * DM + lane * 16;
  };

  float m = -INFINITY, l = 0.0f;
  float acc[16];
  #pragma unroll
  for (int j = 0; j < 16; ++j) acc[j] = 0.0f;

  int t = sub;
  if (t < npos) {
    size_t a = pos_addr(t);
    bf16x8 k0 = *(const bf16x8*)(K + a), k1 = *(const bf16x8*)(K + a + 8);
    bf16x8 v0 = *(const bf16x8*)(V + a), v1 = *(const bf16x8*)(V + a + 8);
    while (true) {
      const int tn = t + 2;
      const bool more = (tn < npos);       // wave-uniform
      bf16x8 nk0, nk1, nv0, nv1;
      if (more) {                          // prefetch next position in subset
        const size_t na = pos_addr(tn);
        nk0 = *(const bf16x8*)(K + na); nk1 = *(const bf16x8*)(K + na + 8);
        nv0 = *(const bf16x8*)(V + na); nv1 = *(const bf16x8*)(V + na + 8);
      }

      float sc = 0.0f;
      #pragma unroll
      for (int j = 0; j < 8; ++j) sc += qf[j] * (float)k0[j] + qf[j + 8] * (float)k1[j];
      sc += __shfl_xor(sc, 1, 64);         // sum across the 4 lanes of this head
      sc += __shfl_xor(sc, 2, 64);

      float mn = fmaxf(m, sc);
      float co = __expf(m - mn);
      float w  = __expf(sc - mn);
      l = l * co + w;
      m = mn;
      #pragma unroll
      for (int j = 0; j < 8; ++j) {
        acc[j]     = acc[j]     * co + w * (float)v0[j];
        acc[j + 8] = acc[j + 8] * co + w * (float)v1[j];
      }

      if (!more) break;
      k0 = nk0; k1 = nk1; v0 = nv0; v1 = nv1;
      t = tn;
    }
  }

  // merge the two partial states per query
  if (sub == 1) {
    sM[ql][lane] = m;
    sL[ql][lane] = l;
    #pragma unroll
    for (int j = 0; j < 16; ++j) sAcc[ql][lane][j] = acc[j];
  }
  __syncthreads();
  if (sub == 0) {
    const float mb = sM[ql][lane], lb = sL[ql][lane];
    const float mt = fmaxf(m, mb);           // m finite (t=0 always valid for sub=0)
    const float ca = __expf(m - mt);
    const float cb = __expf(mb - mt);        // mb=-inf (i==0 case) -> cb=0, exact no-op
    const float inv = 1.0f / (l * ca + lb * cb);
    bf16x8 o0, o1;
    #pragma unroll
    for (int j = 0; j < 8; ++j) {
      o0[j] = (bf16_t)((acc[j]     * ca + sAcc[ql][lane][j]     * cb) * inv);
      o1[j] = (bf16_t)((acc[j + 8] * ca + sAcc[ql][lane][j + 8] * cb) * inv);
    }
    *(bf16x8*)(O + base)     = o0;
    *(bf16x8*)(O + base + 8) = o1;
  }
}

extern "C" void kernel_launch(void* const* d_in, const int* in_sizes, int n_in,
                              void* d_out, int out_size, void* d_ws, size_t ws_size,
                              hipStream_t stream) {
  (void)in_sizes; (void)n_in; (void)out_size; (void)ws_size;
  const float* x  = (const float*)d_in[0];
  const float* qw = (const float*)d_in[1];
  const float* kw = (const float*)d_in[2];
  const float* vw = (const float*)d_in[3];
  const float* ow = (const float*)d_in[4];
  // d_in[5] (positions) and d_in[6] (attend_mask) recomputed analytically in-kernel
  float* out = (float*)d_out;

  bf16_t* Xb  = (bf16_t*)d_ws;                       // 8192x1024
  bf16_t* Qb  = Xb  + (size_t)SEQ * DM;
  bf16_t* Kb  = Qb  + (size_t)SEQ * DM;
  bf16_t* Vb  = Kb  + (size_t)SEQ * DM;
  bf16_t* QWb = Vb  + (size_t)SEQ * DM;              // 1024x1024 x4
  bf16_t* KWb = QWb + (size_t)DM * DM;
  bf16_t* VWb = KWb + (size_t)DM * DM;
  bf16_t* OWb = VWb + (size_t)DM * DM;
  bf16_t* AO  = Qb;  // alias Q: each attn block reads its own q rows before writing them

  cvt_all<<<dim3(8192 + 4096), dim3(256), 0, stream>>>(x, qw, kw, vw, ow,
                                                       Xb, QWb, KWb, VWb, OWb);

  gemm_qkv<<<dim3(SEQ / 256, DM / 128, 3), dim3(256), 0, stream>>>(Xb, QWb, KWb, VWb, Qb, Kb, Vb);
  dilated_attn<<<dim3(SEQ / 2), dim3(256), 0, stream>>>(Qb, Kb, Vb, AO);
  gemm_out<<<dim3(SEQ / 128, DM / 128), dim3(256), 0, stream>>>(AO, OWb, out);
}

// Round 5
// 213.735 us; speedup vs baseline: 1.3464x; 1.1097x over previous
//
#include <hip/hip_runtime.h>
#include <hip/hip_bf16.h>

typedef __bf16 bf16_t;
typedef __bf16 bf16x4 __attribute__((ext_vector_type(4)));
typedef __bf16 bf16x8 __attribute__((ext_vector_type(8)));
typedef float floatx16 __attribute__((ext_vector_type(16)));

#define SEQ    8192
#define DM     1024
#define NHEADS 16
#define HDIM   64

// async global->LDS, 16B per lane; LDS dest is wave-uniform base + lane*16
__device__ __forceinline__ void async_ld16(bf16_t* lds, const bf16_t* g) {
  __builtin_amdgcn_global_load_lds(
      (__attribute__((address_space(1))) void*)g,
      (__attribute__((address_space(3))) void*)lds, 16, 0, 0);
}

// one launch converts x (8192 blocks) + 4 weight matrices (1024 blocks each)
__global__ __launch_bounds__(256)
void cvt_all(const float* __restrict__ x,  const float* __restrict__ qw,
             const float* __restrict__ kw, const float* __restrict__ vw,
             const float* __restrict__ ow,
             bf16_t* __restrict__ Xb,  bf16_t* __restrict__ QWb,
             bf16_t* __restrict__ KWb, bf16_t* __restrict__ VWb,
             bf16_t* __restrict__ OWb) {
  const int b = blockIdx.x;
  const float* in; bf16_t* out; int g;
  if (b < 8192) { in = x; out = Xb; g = b; }
  else {
    const int w  = (b - 8192) >> 10;
    const int wb = (b - 8192) & 1023;
    switch (w) {
      case 0:  in = qw; out = QWb; break;
      case 1:  in = kw; out = KWb; break;
      case 2:  in = vw; out = VWb; break;
      default: in = ow; out = OWb; break;
    }
    g = wb;
  }
  const int idx = (g * 256 + threadIdx.x) * 4;
  float4 v = *(const float4*)(in + idx);
  bf16x4 o = { (bf16_t)v.x, (bf16_t)v.y, (bf16_t)v.z, (bf16_t)v.w };
  *(bf16x4*)(out + idx) = o;
}

// ---------- QKV projection: round-0 VERIFIED kernel, byte-for-byte ----------
// 128x128 tile, BK=64, 4 waves (wave tile 64x64 = 2x2 of 32x32), 32KB LDS,
// 80 VGPR -> 4-5 co-resident blocks/CU. The drain stall at __syncthreads is
// hidden by INTER-BLOCK overlap (m114) -- measured 64.2 us / 802 TF.
// Rounds 1-4 ledger: every larger-wave-tile / in-flight-prefetch variant
// regressed (70.5 / 107 / 101.6 / 86.2 us): bigger acc -> VGPR 144 -> waves/CU
// halve at 128 (m69) -> co-residency lost, which was the actual mechanism.
// LDS: XOR-8 swizzle, slot c of row r holds global chunk c^(r&7) (conflicts
// ~6.3M, free 2-way level). A/B frag: m=lane&31, k=(lane>>5)*8+j.
// C/D: col=lane&31, row=(reg&3)+8*(reg>>2)+4*(lane>>5) [m74/m101].
__global__ __launch_bounds__(256)
void gemm_qkv(const bf16_t* __restrict__ A,
              const bf16_t* __restrict__ Bq, const bf16_t* __restrict__ Bk,
              const bf16_t* __restrict__ Bv,
              bf16_t* __restrict__ Cq, bf16_t* __restrict__ Ck, bf16_t* __restrict__ Cv)
{
  const bf16_t* B = (blockIdx.z == 0) ? Bq : (blockIdx.z == 1) ? Bk : Bv;
  bf16_t*       C = (blockIdx.z == 0) ? Cq : (blockIdx.z == 1) ? Ck : Cv;
  constexpr int Kdim = DM;
  __shared__ __attribute__((aligned(16))) bf16_t sA[128 * 64];   // 16 KB
  __shared__ __attribute__((aligned(16))) bf16_t sB[128 * 64];   // 16 KB

  const int tid  = threadIdx.x;
  const int wave = tid >> 6;
  const int lane = tid & 63;
  const int l31  = lane & 31;
  const int half = lane >> 5;
  const int wr   = (wave >> 1) * 64;
  const int wc   = (wave & 1) * 64;

  const int gc = (lane & 7) ^ ((lane >> 3) & 7);   // swizzled fetch chunk
  const size_t arow0 = (size_t)blockIdx.x * 128 + wave * 32 + (lane >> 3);
  const size_t brow0 = (size_t)blockIdx.y * 128 + wave * 32 + (lane >> 3);
  const bf16_t* Ag = A + arow0 * Kdim + gc * 8;
  const bf16_t* Bg = B + brow0 * Kdim + gc * 8;
  bf16_t* sAw = sA + wave * 32 * 64;
  bf16_t* sBw = sB + wave * 32 * 64;

  floatx16 acc[2][2];
  #pragma unroll
  for (int i = 0; i < 2; ++i)
    #pragma unroll
    for (int j = 0; j < 2; ++j)
      acc[i][j] = (floatx16)(0.0f);

  const int sw = l31 & 7;                 // read-side swizzle key (rows = l31 mod 8)

  for (int ko = 0; ko < Kdim; ko += 64) {
    #pragma unroll
    for (int n = 0; n < 4; ++n) {
      async_ld16(sAw + n * 512, Ag + (size_t)n * 8 * Kdim + ko);
      async_ld16(sBw + n * 512, Bg + (size_t)n * 8 * Kdim + ko);
    }
    __syncthreads();   // drains vmcnt, then barrier

    #pragma unroll
    for (int s = 0; s < 4; ++s) {         // four K=16 sub-steps
      const int ck   = s * 2 + half;      // 16B chunk within 128B row
      const int slot = (ck ^ sw) * 8;     // swizzled slot (elements)
      bf16x8 af[2], bfr[2];
      #pragma unroll
      for (int mi = 0; mi < 2; ++mi)
        af[mi] = *(const bf16x8*)&sA[(wr + mi * 32 + l31) * 64 + slot];
      #pragma unroll
      for (int ni = 0; ni < 2; ++ni)
        bfr[ni] = *(const bf16x8*)&sB[(wc + ni * 32 + l31) * 64 + slot];

      #pragma unroll
      for (int mi = 0; mi < 2; ++mi)
        #pragma unroll
        for (int ni = 0; ni < 2; ++ni)
          acc[mi][ni] = __builtin_amdgcn_mfma_f32_32x32x16_bf16(af[mi], bfr[ni], acc[mi][ni], 0, 0, 0);
    }

    __syncthreads();   // protect LDS before next stage overwrites
  }

  // C/D: col = lane&31, row = (reg&3) + 8*(reg>>2) + 4*(lane>>5)  [m74/m101]
  const float scl = (blockIdx.z == 0) ? 0.125f : 1.0f;   // fold 1/sqrt(64) into Q
  const int crow0 = blockIdx.x * 128 + wr + 4 * half;
  const int ccol0 = blockIdx.y * 128 + wc + l31;
  #pragma unroll
  for (int mi = 0; mi < 2; ++mi)
    #pragma unroll
    for (int ni = 0; ni < 2; ++ni)
      #pragma unroll
      for (int r = 0; r < 16; ++r) {
        const int row = crow0 + mi * 32 + (r & 3) + 8 * (r >> 2);
        C[(size_t)row * DM + (ccol0 + ni * 32)] = (bf16_t)(acc[mi][ni][r] * scl);
      }
}

// ---------- Output projection: SAME proven geometry (BM=128, BN=128, BK=64) ----------
// Round-5 change vs round 0: out-GEMM upgraded from BN=64/BK=32 (wave 64x32,
// ~290 TF class: 3 b128 reads per 2 MFMA + 32 drain-barriers) to the qkv
// geometry (wave 64x64, 16 K-tiles) -- identical inner code to gemm_qkv,
// ran+passed in round 4. 17.2 GFLOP -> predicted ~22 us.
__global__ __launch_bounds__(256)
void gemm_out(const bf16_t* __restrict__ A, const bf16_t* __restrict__ B,
              float* __restrict__ C)
{
  constexpr int Kdim = DM;
  __shared__ __attribute__((aligned(16))) bf16_t sA[128 * 64];   // 16 KB
  __shared__ __attribute__((aligned(16))) bf16_t sB[128 * 64];   // 16 KB

  const int tid  = threadIdx.x;
  const int wave = tid >> 6;
  const int lane = tid & 63;
  const int l31  = lane & 31;
  const int half = lane >> 5;
  const int wr   = (wave >> 1) * 64;
  const int wc   = (wave & 1) * 64;

  const int gc = (lane & 7) ^ ((lane >> 3) & 7);
  const size_t arow0 = (size_t)blockIdx.x * 128 + wave * 32 + (lane >> 3);
  const size_t brow0 = (size_t)blockIdx.y * 128 + wave * 32 + (lane >> 3);
  const bf16_t* Ag = A + arow0 * Kdim + gc * 8;
  const bf16_t* Bg = B + brow0 * Kdim + gc * 8;
  bf16_t* sAw = sA + wave * 32 * 64;
  bf16_t* sBw = sB + wave * 32 * 64;

  floatx16 acc[2][2];
  #pragma unroll
  for (int i = 0; i < 2; ++i)
    #pragma unroll
    for (int j = 0; j < 2; ++j)
      acc[i][j] = (floatx16)(0.0f);

  const int sw = l31 & 7;

  for (int ko = 0; ko < Kdim; ko += 64) {
    #pragma unroll
    for (int n = 0; n < 4; ++n) {
      async_ld16(sAw + n * 512, Ag + (size_t)n * 8 * Kdim + ko);
      async_ld16(sBw + n * 512, Bg + (size_t)n * 8 * Kdim + ko);
    }
    __syncthreads();

    #pragma unroll
    for (int s = 0; s < 4; ++s) {
      const int ck   = s * 2 + half;
      const int slot = (ck ^ sw) * 8;
      bf16x8 af[2], bfr[2];
      #pragma unroll
      for (int mi = 0; mi < 2; ++mi)
        af[mi] = *(const bf16x8*)&sA[(wr + mi * 32 + l31) * 64 + slot];
      #pragma unroll
      for (int ni = 0; ni < 2; ++ni)
        bfr[ni] = *(const bf16x8*)&sB[(wc + ni * 32 + l31) * 64 + slot];

      #pragma unroll
      for (int mi = 0; mi < 2; ++mi)
        #pragma unroll
        for (int ni = 0; ni < 2; ++ni)
          acc[mi][ni] = __builtin_amdgcn_mfma_f32_32x32x16_bf16(af[mi], bfr[ni], acc[mi][ni], 0, 0, 0);
    }

    __syncthreads();
  }

  const int crow0 = blockIdx.x * 128 + wr + 4 * half;
  const int ccol0 = blockIdx.y * 128 + wc + l31;
  #pragma unroll
  for (int mi = 0; mi < 2; ++mi)
    #pragma unroll
    for (int ni = 0; ni < 2; ++ni)
      #pragma unroll
      for (int r = 0; r < 16; ++r) {
        const int row = crow0 + mi * 32 + (r & 3) + 8 * (r >> 2);
        C[(size_t)row * DM + (ccol0 + ni * 32)] = acc[mi][ni][r];
      }
}

// ---------- Attention: SPLIT-WAVE (unchanged; awaiting counters) ----------
// 2 waves per query: wave sub handles positions t = sub, sub+2, ...; partial
// (m, l, acc[16]) states merge through LDS with one exp-rescale.
// Lane L owns dims [16L,16L+16) (head = L>>2); Q arrives pre-scaled.
__global__ __launch_bounds__(256)
void dilated_attn(const bf16_t* __restrict__ Q, const bf16_t* __restrict__ K,
                  const bf16_t* __restrict__ V, bf16_t* O)
{
  __shared__ float sM[2][64];
  __shared__ float sL[2][64];
  __shared__ float sAcc[2][64][17];   // stride 17: gcd(17,32)=1 -> conflict-free

  const int lane = threadIdx.x & 63;
  const int wv   = threadIdx.x >> 6;   // 0..3
  const int ql   = wv >> 1;            // query within block (0,1)
  const int sub  = wv & 1;             // position-parity subset
  const int qb   = (blockIdx.x & 7) * 512 + (blockIdx.x >> 3);  // XCD-affinity swizzle
  const int i    = qb * 2 + ql;
  const size_t base = (size_t)i * DM + lane * 16;

  bf16x8 q0 = *(const bf16x8*)(Q + base);
  bf16x8 q1 = *(const bf16x8*)(Q + base + 8);
  float qf[16];
  #pragma unroll
  for (int j = 0; j < 8; ++j) { qf[j] = (float)q0[j]; qf[j + 8] = (float)q1[j]; }

  // npos = 1 (i==0) else floor(log2 i) + 2   (wave-uniform)
  const int npos = (i == 0) ? 1 : (33 - __builtin_clz((unsigned)i));
  auto pos_addr = [&](int t) -> size_t {
    const int off = (t == 0) ? 0 : (1 << (t - 1));
    return (size_t)(i - off) * DM + lane * 16;
  };

  float m = -INFINITY, l = 0.0f;
  float acc[16];
  #pragma unroll
  for (int j = 0; j < 16; ++j) acc[j] = 0.0f;

  int t = sub;
  if (t < npos) {
    size_t a = pos_addr(t);
    bf16x8 k0 = *(const bf16x8*)(K + a), k1 = *(const bf16x8*)(K + a + 8);
    bf16x8 v0 = *(const bf16x8*)(V + a), v1 = *(const bf16x8*)(V + a + 8);
    while (true) {
      const int tn = t + 2;
      const bool more = (tn < npos);       // wave-uniform
      bf16x8 nk0, nk1, nv0, nv1;
      if (more) {                          // prefetch next position in subset
        const size_t na = pos_addr(tn);
        nk0 = *(const bf16x8*)(K + na); nk1 = *(const bf16x8*)(K + na + 8);
        nv0 = *(const bf16x8*)(V + na); nv1 = *(const bf16x8*)(V + na + 8);
      }

      float sc = 0.0f;
      #pragma unroll
      for (int j = 0; j < 8; ++j) sc += qf[j] * (float)k0[j] + qf[j + 8] * (float)k1[j];
      sc += __shfl_xor(sc, 1, 64);         // sum across the 4 lanes of this head
      sc += __shfl_xor(sc, 2, 64);

      float mn = fmaxf(m, sc);
      float co = __expf(m - mn);
      float w  = __expf(sc - mn);
      l = l * co + w;
      m = mn;
      #pragma unroll
      for (int j = 0; j < 8; ++j) {
        acc[j]     = acc[j]     * co + w * (float)v0[j];
        acc[j + 8] = acc[j + 8] * co + w * (float)v1[j];
      }

      if (!more) break;
      k0 = nk0; k1 = nk1; v0 = nv0; v1 = nv1;
      t = tn;
    }
  }

  // merge the two partial states per query
  if (sub == 1) {
    sM[ql][lane] = m;
    sL[ql][lane] = l;
    #pragma unroll
    for (int j = 0; j < 16; ++j) sAcc[ql][lane][j] = acc[j];
  }
  __syncthreads();
  if (sub == 0) {
    const float mb = sM[ql][lane], lb = sL[ql][lane];
    const float mt = fmaxf(m, mb);           // m finite (t=0 always valid for sub=0)
    const float ca = __expf(m - mt);
    const float cb = __expf(mb - mt);        // mb=-inf (i==0 case) -> cb=0, exact no-op
    const float inv = 1.0f / (l * ca + lb * cb);
    bf16x8 o0, o1;
    #pragma unroll
    for (int j = 0; j < 8; ++j) {
      o0[j] = (bf16_t)((acc[j]     * ca + sAcc[ql][lane][j]     * cb) * inv);
      o1[j] = (bf16_t)((acc[j + 8] * ca + sAcc[ql][lane][j + 8] * cb) * inv);
    }
    *(bf16x8*)(O + base)     = o0;
    *(bf16x8*)(O + base + 8) = o1;
  }
}

extern "C" void kernel_launch(void* const* d_in, const int* in_sizes, int n_in,
                              void* d_out, int out_size, void* d_ws, size_t ws_size,
                              hipStream_t stream) {
  (void)in_sizes; (void)n_in; (void)out_size; (void)ws_size;
  const float* x  = (const float*)d_in[0];
  const float* qw = (const float*)d_in[1];
  const float* kw = (const float*)d_in[2];
  const float* vw = (const float*)d_in[3];
  const float* ow = (const float*)d_in[4];
  // d_in[5] (positions) and d_in[6] (attend_mask) recomputed analytically in-kernel
  float* out = (float*)d_out;

  bf16_t* Xb  = (bf16_t*)d_ws;                       // 8192x1024
  bf16_t* Qb  = Xb  + (size_t)SEQ * DM;
  bf16_t* Kb  = Qb  + (size_t)SEQ * DM;
  bf16_t* Vb  = Kb  + (size_t)SEQ * DM;
  bf16_t* QWb = Vb  + (size_t)SEQ * DM;              // 1024x1024 x4
  bf16_t* KWb = QWb + (size_t)DM * DM;
  bf16_t* VWb = KWb + (size_t)DM * DM;
  bf16_t* OWb = VWb + (size_t)DM * DM;
  bf16_t* AO  = Qb;  // alias Q: each attn block reads its own q rows before writing them

  cvt_all<<<dim3(8192 + 4096), dim3(256), 0, stream>>>(x, qw, kw, vw, ow,
                                                       Xb, QWb, KWb, VWb, OWb);

  gemm_qkv<<<dim3(SEQ / 128, DM / 128, 3), dim3(256), 0, stream>>>(Xb, QWb, KWb, VWb, Qb, Kb, Vb);
  dilated_attn<<<dim3(SEQ / 2), dim3(256), 0, stream>>>(Qb, Kb, Vb, AO);
  gemm_out<<<dim3(SEQ / 128, DM / 128), dim3(256), 0, stream>>>(AO, OWb, out);
}